// Round 1
// 365.116 us; speedup vs baseline: 1.0248x; 1.0248x over previous
//
#include <hip/hip_runtime.h>
#include <stdint.h>

// MegatronAttention: B=2, S=2048, H=2048, NH=16, DH=128.
// KEY INSIGHT: reference einsum 'bhqk,bhkd->bhkd' sums over q ->
//   values[b,h,k,d] = colsum_q(probs)[b,h,k] * v[b,h,k,d].
// Pipeline: convert->bf16, QKV GEMM (scatter epilogue, Q pre-scaled by
// 1/sqrt(d)*log2e), l-pass (writes 1/rowsum directly), cs-pass (weighted
// col sums + fused V scale), output GEMM.
// R6: QKV GEMM rebuilt as 8-wave 256x192 tile, BK=32, 4-buffer LDS ring
// (112 KiB dynamic), counted vmcnt(8) pipeline 3 tiles deep, one barrier
// per K-tile, setprio around MFMA clusters (T3+T4+T5). 512 blocks = 2
// exact full rounds on 256 CUs. Output GEMM + attn unchanged.

typedef __bf16 bf16_t;
typedef __bf16 bf16x8v __attribute__((ext_vector_type(8)));
typedef __bf16 bf16x4v __attribute__((ext_vector_type(4)));
typedef float  f32x4v  __attribute__((ext_vector_type(4)));

#define DEVINL __device__ __forceinline__

// async global->LDS DMA, 16B per lane. LDS dest is wave-uniform base;
// HW writes lane i's data at base + i*16.
DEVINL void gll16(const bf16_t* g, void* lds_wave_uniform_base) {
    __builtin_amdgcn_global_load_lds(
        (__attribute__((address_space(1))) void*)g,
        (__attribute__((address_space(3))) void*)lds_wave_uniform_base,
        16, 0, 0);
}

// ---------------------------------------------------------------- converts
__global__ void conv_x_k(const float* __restrict__ in, bf16_t* __restrict__ out) {
    size_t i = ((size_t)blockIdx.x * 256 + threadIdx.x) * 4;
    float4 v = *reinterpret_cast<const float4*>(in + i);
    bf16x4v o;
    o[0] = (__bf16)v.x; o[1] = (__bf16)v.y; o[2] = (__bf16)v.z; o[3] = (__bf16)v.w;
    *reinterpret_cast<bf16x4v*>(out + i) = o;
}

// out[n][k] = (bf16) in[k][n]   (in: K x N fp32, out: N x K bf16)
__global__ void conv_wT_k(const float* __restrict__ in, bf16_t* __restrict__ out,
                          int K, int N) {
    __shared__ float t[64][33];
    int n0 = blockIdx.x * 32, k0 = blockIdx.y * 64;
    int tn = threadIdx.x & 31, tk = threadIdx.x >> 5;   // tk in 0..7
#pragma unroll
    for (int i = 0; i < 64; i += 8)
        t[tk + i][tn] = in[(size_t)(k0 + tk + i) * N + n0 + tn];
    __syncthreads();
    int n = threadIdx.x >> 3, kg = threadIdx.x & 7;
    bf16x8v o;
#pragma unroll
    for (int i = 0; i < 8; ++i) o[i] = (__bf16)t[kg * 8 + i][n];
    *reinterpret_cast<bf16x8v*>(out + (size_t)(n0 + n) * K + k0 + kg * 8) = o;
}

// ---------------------------------------------------------------- QKV GEMM (R6)
// C[4096,6144] = Xb[4096,2048] @ WqkvT[6144,2048]^T with scatter epilogue.
// Tile 256(M) x 192(N), BK=32, 512 threads = 8 waves as 2(M) x 4(N); each
// wave owns 128x48 (acc 8x3 f32x4 = 96 VGPR). LDS: 4 ring buffers of
// [448 rows x 64B] = 4 x 28 KiB = 112 KiB (rows 0-255 = A, 256-447 = B).
// Swizzle: 64B row = 4 chunks of 16B; content chunk cc lives at slot
// j = cc ^ ((row>>1)&3)  -> ds_read_b128 frag fetch is 2-way on banks
// (free, m136). gll16 writes linearly; swizzle applied to GLOBAL src.
// Staging: 4 rounds of 112 rows; threads 0..447 (waves 0-6) issue exactly
// 4 gll16 per K-tile, wave 7 none -> wave-uniform vmcnt counts.
// Schedule per K-tile t: s_waitcnt vmcnt(8) [tiles t+1,t+2 stay in
// flight], s_barrier, then 2 phases {issue 2 gll16 for tile t+3 into
// buf[(t+3)&3] | ds_read frags | setprio(1) 12 MFMA setprio(0)}.
// buf[(t+3)&3] was last read at tile t-1, barrier-separated -> race-free.
// Epilogue drains vmcnt 8 -> 4 -> 0 over the last two tiles.
#define WAITVM(n) asm volatile("s_waitcnt vmcnt(" #n ")" ::: "memory")

__launch_bounds__(512, 2)
__global__ void qkv8_k(const bf16_t* __restrict__ A, const bf16_t* __restrict__ Bm,
                       bf16_t* __restrict__ Qb, bf16_t* __restrict__ Kb,
                       bf16_t* __restrict__ Vb)
{
    extern __shared__ __align__(16) char smem[];   // 114688 B
    constexpr int K = 2048, NT = 64;               // K-tiles of 32
    constexpr int BUF = 28672;                     // 448*64 B per buffer
    const int tid  = threadIdx.x;
    const int lane = tid & 63, wave = tid >> 6;
    const int quad = lane >> 4, l15 = lane & 15;
    const int rowBase = blockIdx.y * 256, colBase = blockIdx.x * 192;
    const int wr = wave >> 2, wc = wave & 3;
    const bool stager = (wave < 7);                // threads 0..447

    // per-thread staging sources (4 rounds of 112 rows over [A(256)|B(192)])
    const bf16_t* sp[4]; uint32_t sdo[4];
#pragma unroll
    for (int r = 0; r < 4; ++r) {
        int row = r * 112 + (tid >> 2);
        if (row > 447) row = 447;                  // lanes 448-511 never load
        int j  = tid & 3;
        int cc = j ^ ((row >> 1) & 3);
        const bf16_t* base = (row < 256)
            ? (A  + (size_t)(rowBase + row) * K)
            : (Bm + (size_t)(colBase + row - 256) * K);
        sp[r]  = base + cc * 8;
        sdo[r] = (uint32_t)(r * 7168 + wave * 1024);
    }
    // frag read byte offsets (within one buffer)
    uint32_t aoff[8], boff[3];
#pragma unroll
    for (int ti = 0; ti < 8; ++ti) {
        int m = wr * 128 + ti * 16 + l15;
        aoff[ti] = (uint32_t)(m * 64 + ((quad ^ ((m >> 1) & 3)) << 4));
    }
#pragma unroll
    for (int tj = 0; tj < 3; ++tj) {
        int rb = 256 + wc * 48 + tj * 16 + l15;
        boff[tj] = (uint32_t)(rb * 64 + ((quad ^ ((rb >> 1) & 3)) << 4));
    }

    // prologue: stage tiles 0,1,2 (12 gll16 per stager thread)
    if (stager) {
#pragma unroll
        for (int tt = 0; tt < 3; ++tt)
#pragma unroll
            for (int r = 0; r < 4; ++r)
                gll16(sp[r] + tt * 32, smem + tt * BUF + sdo[r]);
    }

    f32x4v acc[8][3] = {};

    auto do_tile = [&](int t, bool stage_on) {
        asm volatile("s_waitcnt lgkmcnt(0)" ::: "memory");  // prior tile's ds_reads done
        __builtin_amdgcn_s_barrier();
        asm volatile("" ::: "memory");
        const char* bp = smem + (size_t)(t & 3) * BUF;
        char*       np = smem + (size_t)((t + 3) & 3) * BUF;
        // ---- phase 0: rows wr*128+0..63
        if (stage_on && stager) {
            gll16(sp[0] + (t + 3) * 32, np + sdo[0]);
            gll16(sp[1] + (t + 3) * 32, np + sdo[1]);
        }
        bf16x8v bv[3], av[4];
#pragma unroll
        for (int tj = 0; tj < 3; ++tj) bv[tj] = *(const bf16x8v*)(bp + boff[tj]);
#pragma unroll
        for (int ti = 0; ti < 4; ++ti) av[ti] = *(const bf16x8v*)(bp + aoff[ti]);
        __builtin_amdgcn_s_setprio(1);
#pragma unroll
        for (int ti = 0; ti < 4; ++ti)
#pragma unroll
            for (int tj = 0; tj < 3; ++tj)
                acc[ti][tj] = __builtin_amdgcn_mfma_f32_16x16x32_bf16(
                                  av[ti], bv[tj], acc[ti][tj], 0, 0, 0);
        __builtin_amdgcn_s_setprio(0);
        // ---- phase 1: rows wr*128+64..127 (bv reused from regs)
        if (stage_on && stager) {
            gll16(sp[2] + (t + 3) * 32, np + sdo[2]);
            gll16(sp[3] + (t + 3) * 32, np + sdo[3]);
        }
#pragma unroll
        for (int ti = 0; ti < 4; ++ti) av[ti] = *(const bf16x8v*)(bp + aoff[4 + ti]);
        __builtin_amdgcn_s_setprio(1);
#pragma unroll
        for (int ti = 0; ti < 4; ++ti)
#pragma unroll
            for (int tj = 0; tj < 3; ++tj)
                acc[4 + ti][tj] = __builtin_amdgcn_mfma_f32_16x16x32_bf16(
                                      av[ti], bv[tj], acc[4 + ti][tj], 0, 0, 0);
        __builtin_amdgcn_s_setprio(0);
    };

    for (int t = 0; t < NT - 2; ++t) {
        WAITVM(8);                      // tiles t+1, t+2 (8 loads) stay in flight
        do_tile(t, t < NT - 3);
    }
    WAITVM(4);
    do_tile(NT - 2, false);
    WAITVM(0);
    do_tile(NT - 1, false);

    // epilogue: scatter-write QKV (identical formulas to proven R5 kernel)
    constexpr float QS = 0.08838834764831845f * 1.44269504088896341f;
#pragma unroll
    for (int ti = 0; ti < 8; ++ti)
#pragma unroll
        for (int tj = 0; tj < 3; ++tj)
#pragma unroll
            for (int r = 0; r < 4; ++r) {
                int m = rowBase + wr * 128 + ti * 16 + quad * 4 + r;
                int n = colBase + wc * 48 + tj * 16 + l15;
                float v = acc[ti][tj][r];
                int b = m >> 11, s = m & 2047;
                int which = n >> 11, hd = n & 2047;
                if (which == 2) {
                    Vb[(size_t)m * 2048 + hd] = (__bf16)v;        // token-major
                } else {
                    if (which == 0) v *= QS;                      // fold softmax scale
                    size_t idx = ((size_t)((b << 4) + (hd >> 7)) * 2048 + s) * 128
                                 + (hd & 127);
                    if (which == 0) Qb[idx] = (__bf16)v; else Kb[idx] = (__bf16)v;
                }
            }
}

// ---------------------------------------------------------------- GEMM (128²)
// Kept for the output projection (N=2048 -> only 128 blocks at 256-wide
// tiles, half the chip idle; 128² gives 512 blocks at 3/CU).
template<int MODE, int N, int K>
__launch_bounds__(256, 3)
__global__ void gemm_bt_k(const bf16_t* __restrict__ A, const bf16_t* __restrict__ Bm,
                          float* __restrict__ outF,
                          bf16_t* __restrict__ Qb, bf16_t* __restrict__ Kb,
                          bf16_t* __restrict__ Vb)
{
    __shared__ __align__(16) bf16_t sA[128 * 64];   // 16 KiB
    __shared__ __align__(16) bf16_t sB[128 * 64];
    const int tid  = threadIdx.x;
    const int lane = tid & 63, wave = tid >> 6;
    const int quad = lane >> 4, l15 = lane & 15;
    const int rowBase = blockIdx.y * 128, colBase = blockIdx.x * 128;
    const int wr0 = (wave >> 1) * 64, wc0 = (wave & 1) * 64;

    const bf16_t* gA[4]; const bf16_t* gB[4]; uint32_t loff[4];
#pragma unroll
    for (int r = 0; r < 4; ++r) {
        int s = r * 256 + wave * 64 + lane;
        int row = s >> 3, j = s & 7;
        int cc = j ^ (row & 7);
        gA[r] = A  + (size_t)(rowBase + row) * K + cc * 8;
        gB[r] = Bm + (size_t)(colBase + row) * K + cc * 8;
        loff[r] = (uint32_t)(r * 256 + wave * 64) * 16;
    }
    int aoff[2][4], boff[2][4];   // [kstep][t] LDS elem offsets
#pragma unroll
    for (int ks = 0; ks < 2; ++ks)
#pragma unroll
        for (int t = 0; t < 4; ++t) {
            int m = wr0 + t * 16 + l15;
            aoff[ks][t] = (m * 8 + ((ks * 4 + quad) ^ (m & 7))) * 8;
            int n = wc0 + t * 16 + l15;
            boff[ks][t] = (n * 8 + ((ks * 4 + quad) ^ (n & 7))) * 8;
        }

    f32x4v acc[4][4] = {};
    for (int kt = 0; kt < K / 64; ++kt) {
        __syncthreads();
#pragma unroll
        for (int r = 0; r < 4; ++r) {
            gll16(gA[r] + kt * 64, (char*)sA + loff[r]);
            gll16(gB[r] + kt * 64, (char*)sB + loff[r]);
        }
        __syncthreads();
#pragma unroll
        for (int ks = 0; ks < 2; ++ks) {
            bf16x8v av[4], bv[4];
#pragma unroll
            for (int t = 0; t < 4; ++t) av[t] = *reinterpret_cast<const bf16x8v*>(sA + aoff[ks][t]);
#pragma unroll
            for (int t = 0; t < 4; ++t) bv[t] = *reinterpret_cast<const bf16x8v*>(sB + boff[ks][t]);
#pragma unroll
            for (int ti = 0; ti < 4; ++ti)
#pragma unroll
                for (int tj = 0; tj < 4; ++tj)
                    acc[ti][tj] = __builtin_amdgcn_mfma_f32_16x16x32_bf16(
                                      av[ti], bv[tj], acc[ti][tj], 0, 0, 0);
        }
    }

    constexpr float QS = 0.08838834764831845f * 1.44269504088896341f;
#pragma unroll
    for (int ti = 0; ti < 4; ++ti)
#pragma unroll
        for (int tj = 0; tj < 4; ++tj)
#pragma unroll
            for (int r = 0; r < 4; ++r) {
                int m = rowBase + wr0 + ti * 16 + quad * 4 + r;   // C row
                int n = colBase + wc0 + tj * 16 + l15;            // C col
                float v = acc[ti][tj][r];
                if constexpr (MODE == 0) {
                    int b = m >> 11, s = m & 2047;
                    int which = n >> 11, hd = n & 2047;
                    if (which == 2) {
                        Vb[(size_t)m * 2048 + hd] = (__bf16)v;
                    } else {
                        if (which == 0) v *= QS;
                        size_t idx = ((size_t)((b << 4) + (hd >> 7)) * 2048 + s) * 128
                                     + (hd & 127);
                        if (which == 0) Qb[idx] = (__bf16)v; else Kb[idx] = (__bf16)v;
                    }
                } else {
                    outF[(size_t)m * N + n] = v;
                }
            }
}

// ---------------------------------------------------------------- attention
// Unsplit: block owns 128 resident rows, sweeps all 2048 streamed rows in
// 32 dbuf'd 64-row tiles. Per-wave: 16 resident frags (64 VGPR), streamed
// half-tile -> 8 ds_read_b128 : 32 MFMA per iter. Grid 512. No atomics to
// global, no memset/recip/vscale kernels.
// Swizzle: 16 chunks of 16B per 256B row, content chunk cc = j ^ (row&7).

__launch_bounds__(256, 2)
__global__ void attn_l_k(const bf16_t* __restrict__ Qb, const bf16_t* __restrict__ Kb,
                         float* __restrict__ rl)
{
    __shared__ __align__(16) bf16_t lds[2][64 * 128];   // 2 x 16 KiB
    const int tid  = threadIdx.x;
    const int lane = tid & 63, wave = tid >> 6;
    const int quad = lane >> 4, l15 = lane & 15;
    const int qt = blockIdx.x, bh = blockIdx.y;
    const bf16_t* Qg = Qb + (size_t)bh * 2048 * 128 + (size_t)qt * 128 * 128;
    const bf16_t* Kg = Kb + (size_t)bh * 2048 * 128;
    const int wr0 = (wave >> 1) * 64;   // resident q rows
    const int wc0 = (wave & 1) * 32;    // streamed half-tile

    int srow[4], scc[4]; uint32_t soff[4];
#pragma unroll
    for (int r = 0; r < 4; ++r) {
        int s = r * 256 + wave * 64 + lane;
        srow[r] = s >> 4; int j = s & 15;
        scc[r] = j ^ (srow[r] & 7);
        soff[r] = (uint32_t)(r * 256 + wave * 64) * 16;
    }
    // stage resident Q (128 rows, 32 KiB) into lds[0..1]
#pragma unroll
    for (int r = 0; r < 4; ++r) {
        gll16(Qg + (size_t)srow[r] * 128 + scc[r] * 8, (char*)lds[0] + soff[r]);
        gll16(Qg + (size_t)(64 + srow[r]) * 128 + scc[r] * 8, (char*)lds[1] + soff[r]);
    }
    __syncthreads();
    bf16x8v qf[4][4];   // [kb][ti] : 64 VGPR, invariant over the sweep
#pragma unroll
    for (int kb = 0; kb < 4; ++kb)
#pragma unroll
        for (int t = 0; t < 4; ++t) {
            int m = wr0 + t * 16 + l15;   // 0..127
            qf[kb][t] = *reinterpret_cast<const bf16x8v*>(
                &lds[0][0] + (m * 16 + ((kb * 4 + quad) ^ (m & 7))) * 8);
        }
    __syncthreads();    // Q reads drained before K overwrites
#pragma unroll
    for (int r = 0; r < 4; ++r)   // prefetch K tile 0
        gll16(Kg + (size_t)srow[r] * 128 + scc[r] * 8, (char*)lds[0] + soff[r]);

    float lsum[4][4] = {};
    for (int it = 0; it < 32; ++it) {
        __syncthreads();   // K[it] staged; prior buf reads done
        const bf16_t* cb = lds[it & 1];
        if (it < 31) {
            char* tgt = (char*)lds[(it & 1) ^ 1];
#pragma unroll
            for (int r = 0; r < 4; ++r)
                gll16(Kg + (size_t)((it + 1) * 64 + srow[r]) * 128 + scc[r] * 8,
                      tgt + soff[r]);
        }
        f32x4v sc[4][2] = {};
#pragma unroll
        for (int kb = 0; kb < 4; ++kb) {
            int ccq = kb * 4 + quad;
            bf16x8v bv[2];
#pragma unroll
            for (int tj = 0; tj < 2; ++tj) {
                int n = wc0 + tj * 16 + l15;   // 0..63
                bv[tj] = *reinterpret_cast<const bf16x8v*>(
                    cb + (n * 16 + (ccq ^ (n & 7))) * 8);
            }
#pragma unroll
            for (int ti = 0; ti < 4; ++ti)
#pragma unroll
                for (int tj = 0; tj < 2; ++tj)
                    sc[ti][tj] = __builtin_amdgcn_mfma_f32_16x16x32_bf16(
                                     qf[kb][ti], bv[tj], sc[ti][tj], 0, 0, 0);
        }
#pragma unroll
        for (int ti = 0; ti < 4; ++ti)
#pragma unroll
            for (int r = 0; r < 4; ++r)
                lsum[ti][r] += __builtin_amdgcn_exp2f(sc[ti][0][r])
                             + __builtin_amdgcn_exp2f(sc[ti][1][r]);
    }
    // reduce across l15 (cols) then across wave pairs (streamed halves)
    __syncthreads();
    float* l_sh = (float*)lds[0];
    if (tid < 128) l_sh[tid] = 0.f;
    __syncthreads();
#pragma unroll
    for (int ti = 0; ti < 4; ++ti)
#pragma unroll
        for (int r = 0; r < 4; ++r) {
            float v = lsum[ti][r];
            v += __shfl_xor(v, 1); v += __shfl_xor(v, 2);
            v += __shfl_xor(v, 4); v += __shfl_xor(v, 8);
            if (l15 == 0) atomicAdd(&l_sh[wr0 + ti * 16 + quad * 4 + r], v);
        }
    __syncthreads();
    if (tid < 128)
        rl[(size_t)bh * 2048 + qt * 128 + tid] = 1.0f / l_sh[tid];
}

__launch_bounds__(256, 2)
__global__ void attn_cs_k(const bf16_t* __restrict__ Qb, const bf16_t* __restrict__ Kb,
                          const float* __restrict__ rl, bf16_t* __restrict__ Vb)
{
    __shared__ __align__(16) bf16_t lds[2][64 * 128];   // 2 x 16 KiB
    const int tid  = threadIdx.x;
    const int lane = tid & 63, wave = tid >> 6;
    const int quad = lane >> 4, l15 = lane & 15;
    const int kt = blockIdx.x, bh = blockIdx.y;
    const bf16_t* Kg = Kb + (size_t)bh * 2048 * 128 + (size_t)kt * 128 * 128;
    const bf16_t* Qg = Qb + (size_t)bh * 2048 * 128;
    const float* rlg = rl + (size_t)bh * 2048;
    const int wcK = (wave >> 1) * 64;   // resident k cols
    const int wq  = (wave & 1) * 32;    // streamed half-tile (q rows)

    int srow[4], scc[4]; uint32_t soff[4];
#pragma unroll
    for (int r = 0; r < 4; ++r) {
        int s = r * 256 + wave * 64 + lane;
        srow[r] = s >> 4; int j = s & 15;
        scc[r] = j ^ (srow[r] & 7);
        soff[r] = (uint32_t)(r * 256 + wave * 64) * 16;
    }
    // stage resident K (128 rows, 32 KiB)
#pragma unroll
    for (int r = 0; r < 4; ++r) {
        gll16(Kg + (size_t)srow[r] * 128 + scc[r] * 8, (char*)lds[0] + soff[r]);
        gll16(Kg + (size_t)(64 + srow[r]) * 128 + scc[r] * 8, (char*)lds[1] + soff[r]);
    }
    __syncthreads();
    bf16x8v kf[4][4];   // [kb][tk]
#pragma unroll
    for (int kb = 0; kb < 4; ++kb)
#pragma unroll
        for (int t = 0; t < 4; ++t) {
            int n = wcK + t * 16 + l15;   // 0..127
            kf[kb][t] = *reinterpret_cast<const bf16x8v*>(
                &lds[0][0] + (n * 16 + ((kb * 4 + quad) ^ (n & 7))) * 8);
        }
    __syncthreads();
#pragma unroll
    for (int r = 0; r < 4; ++r)   // prefetch Q tile 0
        gll16(Qg + (size_t)srow[r] * 128 + scc[r] * 8, (char*)lds[0] + soff[r]);

    float csum[4] = {};
    for (int it = 0; it < 32; ++it) {
        __syncthreads();
        const bf16_t* cb = lds[it & 1];
        if (it < 31) {
            char* tgt = (char*)lds[(it & 1) ^ 1];
#pragma unroll
            for (int r = 0; r < 4; ++r)
                gll16(Qg + (size_t)((it + 1) * 64 + srow[r]) * 128 + scc[r] * 8,
                      tgt + soff[r]);
        }
        f32x4v sc[2][4] = {};
#pragma unroll
        for (int kb = 0; kb < 4; ++kb) {
            int ccq = kb * 4 + quad;
            bf16x8v av[2];
#pragma unroll
            for (int ta = 0; ta < 2; ++ta) {
                int m = wq + ta * 16 + l15;   // 0..63 streamed q rows
                av[ta] = *reinterpret_cast<const bf16x8v*>(
                    cb + (m * 16 + (ccq ^ (m & 7))) * 8);
            }
#pragma unroll
            for (int ta = 0; ta < 2; ++ta)
#pragma unroll
                for (int tk = 0; tk < 4; ++tk)
                    sc[ta][tk] = __builtin_amdgcn_mfma_f32_16x16x32_bf16(
                                     av[ta], kf[kb][tk], sc[ta][tk], 0, 0, 0);
        }
#pragma unroll
        for (int ta = 0; ta < 2; ++ta) {
            f32x4v rlv = *reinterpret_cast<const f32x4v*>(
                rlg + it * 64 + wq + ta * 16 + quad * 4);
#pragma unroll
            for (int r = 0; r < 4; ++r)
#pragma unroll
                for (int tk = 0; tk < 4; ++tk)
                    csum[tk] += __builtin_amdgcn_exp2f(sc[ta][tk][r]) * rlv[r];
        }
    }
    // col-reduce across quads, then across wave pairs via LDS
    __syncthreads();
    float* cs_sh = (float*)lds[0];
    if (tid < 128) cs_sh[tid] = 0.f;
    __syncthreads();
#pragma unroll
    for (int tk = 0; tk < 4; ++tk) {
        float v = csum[tk];
        v += __shfl_xor(v, 16); v += __shfl_xor(v, 32);
        if (quad == 0) atomicAdd(&cs_sh[wcK + tk * 16 + l15], v);
    }
    __syncthreads();
    // fused: scale this block's disjoint 128x128 V patch in place
    int b = bh >> 4, h = bh & 15;
#pragma unroll
    for (int r = 0; r < 8; ++r) {
        int s = r * 256 + tid;
        int row = s >> 4, jc = s & 15;
        size_t off = ((size_t)(b * 2048 + kt * 128 + row)) * 2048 + h * 128 + jc * 8;
        float csv = cs_sh[row];
        bf16x8v vv = *reinterpret_cast<const bf16x8v*>(Vb + off);
        bf16x8v ov;
#pragma unroll
        for (int i = 0; i < 8; ++i) ov[i] = (__bf16)((float)vv[i] * csv);
        *reinterpret_cast<bf16x8v*>(Vb + off) = ov;
    }
}

// ---------------------------------------------------------------- launch
extern "C" void kernel_launch(void* const* d_in, const int* in_sizes, int n_in,
                              void* d_out, int out_size, void* d_ws, size_t ws_size,
                              hipStream_t stream) {
    (void)in_sizes; (void)n_in; (void)out_size; (void)ws_size;
    const float* x     = (const float*)d_in[0];
    const float* w_qkv = (const float*)d_in[1];
    const float* w_o   = (const float*)d_in[2];
    float* out = (float*)d_out;

    static int inited = 0;
    if (!inited) {
        (void)hipFuncSetAttribute((const void*)qkv8_k,
                                  hipFuncAttributeMaxDynamicSharedMemorySize, 114688);
        inited = 1;
    }

    char* w = (char*)d_ws;
    auto alloc = [&](size_t bytes) {
        char* p = w; w += (bytes + 255) & ~(size_t)255; return p;
    };
    bf16_t* Xb    = (bf16_t*)alloc(4096ull * 2048 * 2);   // 16 MiB
    bf16_t* WqkvT = (bf16_t*)alloc(6144ull * 2048 * 2);   // 24 MiB
    bf16_t* WoT   = (bf16_t*)alloc(2048ull * 2048 * 2);   //  8 MiB
    bf16_t* Qb    = (bf16_t*)alloc(32ull * 2048 * 128 * 2); // 16 MiB [bh][s][d]
    bf16_t* Kb    = (bf16_t*)alloc(32ull * 2048 * 128 * 2);
    bf16_t* Vb    = (bf16_t*)alloc(4096ull * 2048 * 2);   // token-major
    float*  rlb   = (float*)alloc(32ull * 2048 * 4);      // 1/l (plain stores)

    conv_x_k <<<8192, 256, 0, stream>>>(x, Xb);
    conv_wT_k<<<dim3(192, 32), 256, 0, stream>>>(w_qkv, WqkvT, 2048, 6144);
    conv_wT_k<<<dim3(64, 32),  256, 0, stream>>>(w_o,   WoT,   2048, 2048);

    qkv8_k<<<dim3(32, 16), 512, 114688, stream>>>(Xb, WqkvT, Qb, Kb, Vb);

    attn_l_k <<<dim3(16, 32), 256, 0, stream>>>(Qb, Kb, rlb);
    attn_cs_k<<<dim3(16, 32), 256, 0, stream>>>(Qb, Kb, rlb, Vb);

    gemm_bt_k<1, 2048, 2048><<<dim3(16, 32), 256, 0, stream>>>(
        Vb, WoT, out, nullptr, nullptr, nullptr);
}